// Round 1
// baseline (329.665 us; speedup 1.0000x reference)
//
#include <hip/hip_runtime.h>
#include <hip/hip_bf16.h>
#include <stdint.h>

#define K_DIM 1024
#define N_DIM 16384

typedef __attribute__((ext_vector_type(8))) short short8;
typedef __attribute__((ext_vector_type(4))) float floatx4;

__device__ __forceinline__ void async_copy16(const void* g, void* l) {
  __builtin_amdgcn_global_load_lds((const __attribute__((address_space(1))) void*)g,
                                   (__attribute__((address_space(3))) void*)l,
                                   16, 0, 0);
}

// round-to-nearest-even f32 -> bf16 bits
__device__ __forceinline__ unsigned short f2bf(float x) {
  uint32_t u = __float_as_uint(x);
  u += 0x7fffu + ((u >> 16) & 1u);
  return (unsigned short)(u >> 16);
}

// ---------------- Alpha fp32 -> bf16 ----------------
__global__ __launch_bounds__(256) void convert_alpha(const float* __restrict__ A,
                                                     unsigned short* __restrict__ Abf) {
  int idx = (blockIdx.x * 256 + threadIdx.x) * 4;
  floatx4 v = *(const floatx4*)(A + idx);
  ushort4 o;
  o.x = f2bf(v[0]); o.y = f2bf(v[1]); o.z = f2bf(v[2]); o.w = f2bf(v[3]);
  *(ushort4*)(Abf + idx) = o;
}

// ---------------- scan: S_{t+1}=decay*(S_t+obs_t), emit Gt[t][j]=beta_j*S_t[j] (bf16)
// also accumulates row sums of obs into mu_acc for Mu0.
// grid: (N/128, K/64), block 256. Halo = 48 (decay<=e^-1 -> err ~1e-20).
__global__ __launch_bounds__(256) void scan_kernel(const float* __restrict__ obs,
                                                   const float* __restrict__ Beta,
                                                   unsigned short* __restrict__ Gt,
                                                   float* __restrict__ mu_acc) {
  __shared__ float tile[64][177];   // 64 rows x (48 halo + 128) cols, odd stride -> no bank conflicts
  const int tw = blockIdx.x;        // time window
  const int jg = blockIdx.y;        // row group
  const int j0 = jg * 64;
  const int t0 = tw * 128;
  const int tid = threadIdx.x;

  // phase 1: cooperative coalesced load of obs[j0:j0+64][t0-48 : t0+128]
  for (int u = tid; u < 64 * 44; u += 256) {
    int row = u / 44;
    int c4 = u % 44;
    int tloc = c4 * 4;
    int tg = t0 - 48 + tloc;
    float4 v;
    if (tg >= 0) {
      v = *(const float4*)(obs + (size_t)(j0 + row) * N_DIM + tg);
    } else {
      v = make_float4(0.f, 0.f, 0.f, 0.f);   // t<0: no events
    }
    tile[row][tloc]     = v.x;
    tile[row][tloc + 1] = v.y;
    tile[row][tloc + 2] = v.z;
    tile[row][tloc + 3] = v.w;
  }
  __syncthreads();

  // Mu0 partial row sums over the main (non-halo) region
  {
    int row = tid & 63;
    int qq = tid >> 6;
    float s = 0.f;
    #pragma unroll 8
    for (int i = 0; i < 32; ++i) s += tile[row][48 + qq * 32 + i];
    atomicAdd(&mu_acc[j0 + row], s);
  }

  // phase 2: each wave scans a 32-step sub-chunk (48-step warm-up from LDS)
  const int w = tid >> 6;
  const int lane = tid & 63;
  const int j = j0 + lane;
  const float beta = Beta[j];
  const float decay = expf(-beta);
  const int lt0 = w * 32;           // local index of halo start
  float S = 0.f;
  #pragma unroll
  for (int i = 0; i < 48; ++i) S = decay * (S + tile[lane][lt0 + i]);
  const int tg = t0 + w * 32;
  #pragma unroll
  for (int i = 0; i < 32; ++i) {
    Gt[(size_t)(tg + i) * K_DIM + j] = f2bf(beta * S);  // wave-contiguous 128B store
    S = decay * (S + tile[lane][lt0 + 48 + i]);
  }
}

// ---------------- NT bf16 MFMA GEMM + fused epilogue ----------------
// C[k][t] = sum_j Alpha[k][j] * Gt[t][j]; lam1 = softplus(C) (0 at t=0);
// writes lam1, accumulates loglik partials.
// BM=BN=128, BK=64, 256 threads (2x2 waves, each wave 64x64 via 4x4 frags of 16x16x32).
__global__ __launch_bounds__(256) void gemm_kernel(const unsigned short* __restrict__ A,   // [1024][1024] bf16
                                                   const unsigned short* __restrict__ B,   // [16384][1024] bf16 (Gt)
                                                   const float* __restrict__ obs,          // [1024][16384]
                                                   const float* __restrict__ mu_acc,       // raw row sums
                                                   float* __restrict__ lam1_out,
                                                   double* __restrict__ acc_out) {
  const int tb = blockIdx.x;   // t tile (0..127)
  const int kb = blockIdx.y;   // k tile (0..7)
  const int tid = threadIdx.x;
  const int lane = tid & 63, w = tid >> 6;
  const int wm = w >> 1, wn = w & 1;
  const int ml = lane & 15, q = lane >> 4;

  __shared__ unsigned short As[128 * 64];
  __shared__ unsigned short Bs[128 * 64];
  __shared__ float wsum[4];

  floatx4 acc[4][4] = {};

  const unsigned short* Ab = A + (size_t)kb * 128 * K_DIM;
  const unsigned short* Bb = B + (size_t)tb * 128 * K_DIM;

  for (int kt = 0; kt < 16; ++kt) {
    const unsigned short* Ak = Ab + kt * 64;
    const unsigned short* Bk = Bb + kt * 64;
    #pragma unroll
    for (int it = 0; it < 4; ++it) {
      int L = w * 256 + it * 64 + lane;      // 16B-chunk id, linear in lane (global_load_lds reqt)
      int r = L >> 3;                        // tile row
      int c = L & 7;                         // LDS chunk within row
      int cg = c ^ (r & 7);                  // XOR swizzle on the GLOBAL side
      async_copy16(Ak + (size_t)r * K_DIM + cg * 8, &As[L * 8]);
      async_copy16(Bk + (size_t)r * K_DIM + cg * 8, &Bs[L * 8]);
    }
    __syncthreads();   // emits vmcnt(0) drain + barrier

    #pragma unroll
    for (int kk = 0; kk < 2; ++kk) {
      short8 a[4], b[4];
      #pragma unroll
      for (int mf = 0; mf < 4; ++mf) {
        int r = wm * 64 + mf * 16 + ml;
        int c = (kk * 4 + q) ^ (r & 7);
        a[mf] = *(const short8*)&As[r * 64 + c * 8];
      }
      #pragma unroll
      for (int nf = 0; nf < 4; ++nf) {
        int r = wn * 64 + nf * 16 + ml;
        int c = (kk * 4 + q) ^ (r & 7);
        b[nf] = *(const short8*)&Bs[r * 64 + c * 8];
      }
      #pragma unroll
      for (int mf = 0; mf < 4; ++mf)
        #pragma unroll
        for (int nf = 0; nf < 4; ++nf)
          acc[mf][nf] = __builtin_amdgcn_mfma_f32_16x16x32_bf16(a[mf], b[nf], acc[mf][nf], 0, 0, 0);
    }
    __syncthreads();
  }

  // epilogue: C/D layout col=lane&15 (t), row=q*4+reg (k)
  float lsum = 0.f;
  const int kblk = kb * 128 + wm * 64;
  const int tblk = tb * 128 + wn * 64;
  #pragma unroll
  for (int mf = 0; mf < 4; ++mf) {
    int k4 = kblk + mf * 16 + q * 4;
    floatx4 mu4 = *(const floatx4*)&mu_acc[k4];
    #pragma unroll
    for (int r = 0; r < 4; ++r) {
      int k = k4 + r;
      float mu = mu4[r] * (1.0f / 163840.0f) + 1e-5f;
      #pragma unroll
      for (int nf = 0; nf < 4; ++nf) {
        int t = tblk + nf * 16 + ml;
        float raw = acc[mf][nf][r];
        float lam = fmaxf(raw, 0.f) + log1pf(expf(-fabsf(raw)));  // stable softplus
        if (t == 0) lam = 0.f;                                     // t=0 branch returns zeros
        lam1_out[(size_t)k * N_DIM + t] = lam;
        float o = obs[(size_t)k * N_DIM + t];
        lsum += o * logf(mu + lam + 1e-5f) - mu - lam;
      }
    }
  }
  // block reduce -> one double atomic
  #pragma unroll
  for (int off = 32; off > 0; off >>= 1) lsum += __shfl_down(lsum, off);
  if (lane == 0) wsum[w] = lsum;
  __syncthreads();
  if (tid == 0) atomicAdd(acc_out, (double)(wsum[0] + wsum[1] + wsum[2] + wsum[3]));
}

// ---------------- lams0 broadcast + loglik store ----------------
__global__ __launch_bounds__(256) void finalize_kernel(const float* __restrict__ mu_acc,
                                                       const double* __restrict__ acc,
                                                       float* __restrict__ out) {
  int k = blockIdx.x;
  float mu = mu_acc[k] * (1.0f / 163840.0f) + 1e-5f;
  float* dst = out + 1 + (size_t)k * N_DIM;
  for (int t = threadIdx.x; t < N_DIM; t += 256) dst[t] = mu;
  if (blockIdx.x == 0 && threadIdx.x == 0) out[0] = (float)(*acc);
}

extern "C" void kernel_launch(void* const* d_in, const int* in_sizes, int n_in,
                              void* d_out, int out_size, void* d_ws, size_t ws_size,
                              hipStream_t stream) {
  const float* obs   = (const float*)d_in[0];   // [1024][16384]
  const float* Beta  = (const float*)d_in[1];   // [1024]
  const float* Alpha = (const float*)d_in[2];   // [1024][1024]
  float* out = (float*)d_out;                   // [0]=loglik, then lams0 (K*N), then lam1 (K*N)

  // small scratch in d_ws: double accumulator @0, mu row sums @16 (16B-aligned)
  double* acc  = (double*)d_ws;
  float* mu_acc = (float*)((char*)d_ws + 16);

  // large scratch hides inside the lams0 output region (written last):
  // Gt bf16 [N][K] = 32MB at out+4 (16B aligned), Alpha bf16 2MB after it. Total 34MB < 64MB region.
  unsigned short* Gt  = (unsigned short*)(out + 4);
  unsigned short* Abf = Gt + (size_t)N_DIM * K_DIM;

  hipMemsetAsync(d_ws, 0, 16 + K_DIM * sizeof(float), stream);

  convert_alpha<<<dim3(K_DIM * K_DIM / (256 * 4)), 256, 0, stream>>>(Alpha, Abf);

  scan_kernel<<<dim3(N_DIM / 128, K_DIM / 64), 256, 0, stream>>>(obs, Beta, Gt, mu_acc);

  gemm_kernel<<<dim3(N_DIM / 128, K_DIM / 128), 256, 0, stream>>>(
      Abf, Gt, obs, mu_acc, out + 1 + (size_t)K_DIM * N_DIM, acc);

  finalize_kernel<<<dim3(K_DIM), 256, 0, stream>>>(mu_acc, acc, out);
}

// Round 2
// 294.661 us; speedup vs baseline: 1.1188x; 1.1188x over previous
//
#include <hip/hip_runtime.h>
#include <hip/hip_bf16.h>
#include <stdint.h>

#define K_DIM 1024
#define N_DIM 16384

typedef __attribute__((ext_vector_type(8))) short short8;
typedef __attribute__((ext_vector_type(4))) float floatx4;

__device__ __forceinline__ void async_copy16(const void* g, void* l) {
  __builtin_amdgcn_global_load_lds((const __attribute__((address_space(1))) void*)g,
                                   (__attribute__((address_space(3))) void*)l,
                                   16, 0, 0);
}

// round-to-nearest-even f32 -> bf16 bits
__device__ __forceinline__ unsigned short f2bf(float x) {
  uint32_t u = __float_as_uint(x);
  u += 0x7fffu + ((u >> 16) & 1u);
  return (unsigned short)(u >> 16);
}

// ---------------- Alpha fp32 -> bf16 ----------------
__global__ __launch_bounds__(256) void convert_alpha(const float* __restrict__ A,
                                                     unsigned short* __restrict__ Abf) {
  int idx = (blockIdx.x * 256 + threadIdx.x) * 4;
  floatx4 v = *(const floatx4*)(A + idx);
  ushort4 o;
  o.x = f2bf(v[0]); o.y = f2bf(v[1]); o.z = f2bf(v[2]); o.w = f2bf(v[3]);
  *(ushort4*)(Abf + idx) = o;
}

// ---------------- Mu0 row sums: one block per row, no atomics ----------------
__global__ __launch_bounds__(256) void mu_kernel(const float* __restrict__ obs,
                                                 float* __restrict__ mu_acc) {
  const int k = blockIdx.x;
  const float* row = obs + (size_t)k * N_DIM;
  float s = 0.f;
  // 16384 / (256*4) = 16 float4 per thread, coalesced
  for (int t = threadIdx.x * 4; t < N_DIM; t += 256 * 4) {
    float4 v = *(const float4*)(row + t);
    s += (v.x + v.y) + (v.z + v.w);
  }
  #pragma unroll
  for (int off = 32; off > 0; off >>= 1) s += __shfl_down(s, off);
  __shared__ float ws[4];
  if ((threadIdx.x & 63) == 0) ws[threadIdx.x >> 6] = s;
  __syncthreads();
  if (threadIdx.x == 0) mu_acc[k] = (ws[0] + ws[1]) + (ws[2] + ws[3]);
}

// ---------------- scan: S_{t+1}=decay*(S_t+obs_t), emit Gt[t][j]=beta_j*S_t[j] (bf16)
// grid: (N/128, K/64), block 256. Halo = 32 (decay<=e^-1 -> trunc err ~5e-15).
__global__ __launch_bounds__(256) void scan_kernel(const float* __restrict__ obs,
                                                   const float* __restrict__ Beta,
                                                   unsigned short* __restrict__ Gt) {
  __shared__ float tile[64][161];   // 64 rows x (32 halo + 128) cols, odd stride -> no conflicts
  const int tw = blockIdx.x;        // time window
  const int jg = blockIdx.y;        // row group
  const int j0 = jg * 64;
  const int t0 = tw * 128;
  const int tid = threadIdx.x;

  // phase 1: cooperative coalesced load of obs[j0:j0+64][t0-32 : t0+128]
  for (int u = tid; u < 64 * 40; u += 256) {
    int row = u / 40;
    int c4 = u % 40;
    int tloc = c4 * 4;
    int tg = t0 - 32 + tloc;
    float4 v;
    if (tg >= 0) {
      v = *(const float4*)(obs + (size_t)(j0 + row) * N_DIM + tg);
    } else {
      v = make_float4(0.f, 0.f, 0.f, 0.f);   // t<0: no events
    }
    tile[row][tloc]     = v.x;
    tile[row][tloc + 1] = v.y;
    tile[row][tloc + 2] = v.z;
    tile[row][tloc + 3] = v.w;
  }
  __syncthreads();

  // phase 2: each wave scans a 32-step sub-chunk (32-step warm-up from LDS)
  const int w = tid >> 6;
  const int lane = tid & 63;
  const int j = j0 + lane;
  const float beta = Beta[j];
  const float decay = expf(-beta);
  const int lt0 = w * 32;           // local index of halo start
  float S = 0.f;
  #pragma unroll
  for (int i = 0; i < 32; ++i) S = decay * (S + tile[lane][lt0 + i]);
  const int tg = t0 + w * 32;
  #pragma unroll
  for (int i = 0; i < 32; ++i) {
    Gt[(size_t)(tg + i) * K_DIM + j] = f2bf(beta * S);  // wave-contiguous 128B store
    S = decay * (S + tile[lane][lt0 + 32 + i]);
  }
}

// ---------------- NT bf16 MFMA GEMM + fused epilogue ----------------
// C[k][t] = sum_j Alpha[k][j] * Gt[t][j]; lam1 = softplus(C) (0 at t=0);
// writes lam1, accumulates loglik partials.
// BM=BN=128, BK=64, 256 threads (2x2 waves, each wave 64x64 via 4x4 frags of 16x16x32).
__global__ __launch_bounds__(256) void gemm_kernel(const unsigned short* __restrict__ A,   // [1024][1024] bf16
                                                   const unsigned short* __restrict__ B,   // [16384][1024] bf16 (Gt)
                                                   const float* __restrict__ obs,          // [1024][16384]
                                                   const float* __restrict__ mu_acc,       // raw row sums
                                                   float* __restrict__ lam1_out,
                                                   double* __restrict__ acc_out) {
  const int tb = blockIdx.x;   // t tile (0..127)
  const int kb = blockIdx.y;   // k tile (0..7)
  const int tid = threadIdx.x;
  const int lane = tid & 63, w = tid >> 6;
  const int wm = w >> 1, wn = w & 1;
  const int ml = lane & 15, q = lane >> 4;

  __shared__ unsigned short As[128 * 64];
  __shared__ unsigned short Bs[128 * 64];
  __shared__ float wsum[4];

  floatx4 acc[4][4] = {};

  const unsigned short* Ab = A + (size_t)kb * 128 * K_DIM;
  const unsigned short* Bb = B + (size_t)tb * 128 * K_DIM;

  for (int kt = 0; kt < 16; ++kt) {
    const unsigned short* Ak = Ab + kt * 64;
    const unsigned short* Bk = Bb + kt * 64;
    #pragma unroll
    for (int it = 0; it < 4; ++it) {
      int L = w * 256 + it * 64 + lane;      // 16B-chunk id, linear in lane (global_load_lds reqt)
      int r = L >> 3;                        // tile row
      int c = L & 7;                         // LDS chunk within row
      int cg = c ^ (r & 7);                  // XOR swizzle on the GLOBAL side
      async_copy16(Ak + (size_t)r * K_DIM + cg * 8, &As[L * 8]);
      async_copy16(Bk + (size_t)r * K_DIM + cg * 8, &Bs[L * 8]);
    }
    __syncthreads();   // emits vmcnt(0) drain + barrier

    #pragma unroll
    for (int kk = 0; kk < 2; ++kk) {
      short8 a[4], b[4];
      #pragma unroll
      for (int mf = 0; mf < 4; ++mf) {
        int r = wm * 64 + mf * 16 + ml;
        int c = (kk * 4 + q) ^ (r & 7);
        a[mf] = *(const short8*)&As[r * 64 + c * 8];
      }
      #pragma unroll
      for (int nf = 0; nf < 4; ++nf) {
        int r = wn * 64 + nf * 16 + ml;
        int c = (kk * 4 + q) ^ (r & 7);
        b[nf] = *(const short8*)&Bs[r * 64 + c * 8];
      }
      #pragma unroll
      for (int mf = 0; mf < 4; ++mf)
        #pragma unroll
        for (int nf = 0; nf < 4; ++nf)
          acc[mf][nf] = __builtin_amdgcn_mfma_f32_16x16x32_bf16(a[mf], b[nf], acc[mf][nf], 0, 0, 0);
    }
    __syncthreads();
  }

  // epilogue: C/D layout col=lane&15 (t), row=q*4+reg (k). Fast-math transcendentals:
  // v_exp_f32/v_log_f32 instead of libm (this was 69% VALUBusy in round 1).
  float lsum = 0.f;
  const int kblk = kb * 128 + wm * 64;
  const int tblk = tb * 128 + wn * 64;
  #pragma unroll
  for (int mf = 0; mf < 4; ++mf) {
    int k4 = kblk + mf * 16 + q * 4;
    floatx4 mu4 = *(const floatx4*)&mu_acc[k4];
    #pragma unroll
    for (int r = 0; r < 4; ++r) {
      int k = k4 + r;
      float mu = mu4[r] * (1.0f / 163840.0f) + 1e-5f;
      #pragma unroll
      for (int nf = 0; nf < 4; ++nf) {
        int t = tblk + nf * 16 + ml;
        float raw = acc[mf][nf][r];
        float e = __expf(-fabsf(raw));
        float lam = fmaxf(raw, 0.f) + __logf(1.f + e);   // stable softplus, fast-math
        if (t == 0) lam = 0.f;                           // t=0 branch returns zeros
        lam1_out[(size_t)k * N_DIM + t] = lam;
        float o = obs[(size_t)k * N_DIM + t];
        lsum += o * __logf(mu + lam + 1e-5f) - mu - lam;
      }
    }
  }
  // block reduce -> one double atomic
  #pragma unroll
  for (int off = 32; off > 0; off >>= 1) lsum += __shfl_down(lsum, off);
  if (lane == 0) wsum[w] = lsum;
  __syncthreads();
  if (tid == 0) atomicAdd(acc_out, (double)(wsum[0] + wsum[1] + wsum[2] + wsum[3]));
}

// ---------------- lams0 broadcast + loglik store ----------------
__global__ __launch_bounds__(256) void finalize_kernel(const float* __restrict__ mu_acc,
                                                       const double* __restrict__ acc,
                                                       float* __restrict__ out) {
  int k = blockIdx.x;
  float mu = mu_acc[k] * (1.0f / 163840.0f) + 1e-5f;
  float* dst = out + 1 + (size_t)k * N_DIM;   // dst is 4B-aligned, ≡1 mod 4 floats
  int tid = threadIdx.x;
  // head: 3 scalars to reach 16B alignment
  if (tid < 3) dst[tid] = mu;
  float4 v4 = make_float4(mu, mu, mu, mu);
  // aligned float4 body: [3, 3+4*4095) ; tail element 16383 scalar
  for (int t = 3 + tid * 4; t + 3 < N_DIM; t += 256 * 4) *(float4*)(dst + t) = v4;
  if (tid == 3) dst[N_DIM - 1] = mu;
  if (blockIdx.x == 0 && tid == 4) out[0] = (float)(*acc);
}

extern "C" void kernel_launch(void* const* d_in, const int* in_sizes, int n_in,
                              void* d_out, int out_size, void* d_ws, size_t ws_size,
                              hipStream_t stream) {
  const float* obs   = (const float*)d_in[0];   // [1024][16384]
  const float* Beta  = (const float*)d_in[1];   // [1024]
  const float* Alpha = (const float*)d_in[2];   // [1024][1024]
  float* out = (float*)d_out;                   // [0]=loglik, then lams0 (K*N), then lam1 (K*N)

  // small scratch in d_ws: double accumulator @0, mu row sums @16 (16B-aligned)
  double* acc   = (double*)d_ws;
  float* mu_acc = (float*)((char*)d_ws + 16);

  // large scratch hides inside the lams0 output region (written last):
  // Gt bf16 [N][K] = 32MB at out+4 (16B aligned), Alpha bf16 2MB after it. Total 34MB < 64MB region.
  unsigned short* Gt  = (unsigned short*)(out + 4);
  unsigned short* Abf = Gt + (size_t)N_DIM * K_DIM;

  hipMemsetAsync(d_ws, 0, 16, stream);   // zero the loglik accumulator only

  convert_alpha<<<dim3(K_DIM * K_DIM / (256 * 4)), 256, 0, stream>>>(Alpha, Abf);

  mu_kernel<<<dim3(K_DIM), 256, 0, stream>>>(obs, mu_acc);

  scan_kernel<<<dim3(N_DIM / 128, K_DIM / 64), 256, 0, stream>>>(obs, Beta, Gt);

  gemm_kernel<<<dim3(N_DIM / 128, K_DIM / 128), 256, 0, stream>>>(
      Abf, Gt, obs, mu_acc, out + 1 + (size_t)K_DIM * N_DIM, acc);

  finalize_kernel<<<dim3(K_DIM), 256, 0, stream>>>(mu_acc, acc, out);
}

// Round 3
// 287.344 us; speedup vs baseline: 1.1473x; 1.0255x over previous
//
#include <hip/hip_runtime.h>
#include <hip/hip_bf16.h>
#include <stdint.h>

#define K_DIM 1024
#define N_DIM 16384

typedef __attribute__((ext_vector_type(4))) float floatx4;

__device__ __forceinline__ void async_copy16(const void* g, void* l) {
  __builtin_amdgcn_global_load_lds((const __attribute__((address_space(1))) void*)g,
                                   (__attribute__((address_space(3))) void*)l,
                                   16, 0, 0);
}

// pack 4 floats -> 4 fp8 e4m3 bytes (HW RNE, saturating)
__device__ __forceinline__ int pk4_e4m3(float a, float b, float c, float d) {
  int lo = __builtin_amdgcn_cvt_pk_fp8_f32(a, b, 0, false);
  return __builtin_amdgcn_cvt_pk_fp8_f32(c, d, lo, true);
}

#define A_SCALE 512.0f   // Alpha in [0,0.01] is subnormal in e4m3 -> scale into [0,5.12]
#define G_SCALE 32.0f    // Gt in [0,~6] -> [0,192] (< 448 max finite)
#define INV_SCALE (1.0f / (512.0f * 32.0f))

// ---------------- Mu0 row sums + Alpha fp32 -> e4m3 (x512), one block per row ----------------
__global__ __launch_bounds__(256) void mu_convert(const float* __restrict__ obs,
                                                  const float* __restrict__ Alpha,
                                                  float* __restrict__ mu_acc,
                                                  int* __restrict__ A8) {   // 256 ints per row
  const int k = blockIdx.x;
  const int tid = threadIdx.x;
  const float* row = obs + (size_t)k * N_DIM;
  float s = 0.f;
  for (int t = tid * 4; t < N_DIM; t += 256 * 4) {
    float4 v = *(const float4*)(row + t);
    s += (v.x + v.y) + (v.z + v.w);
  }
  #pragma unroll
  for (int off = 32; off > 0; off >>= 1) s += __shfl_down(s, off);
  __shared__ float ws[4];
  if ((tid & 63) == 0) ws[tid >> 6] = s;
  // Alpha row conversion (independent of the reduction)
  float4 av = *(const float4*)(Alpha + (size_t)k * K_DIM + tid * 4);
  A8[k * 256 + tid] = pk4_e4m3(av.x * A_SCALE, av.y * A_SCALE, av.z * A_SCALE, av.w * A_SCALE);
  __syncthreads();
  if (tid == 0) mu_acc[k] = (ws[0] + ws[1]) + (ws[2] + ws[3]);
}

// ---------------- scan: S_{t+1}=decay*(S_t+obs_t), emit Gt8[t][j]=e4m3(32*beta*S_t[j])
// grid: (N/128, K/64), block 256. Halo = 32 (decay<=e^-1 -> trunc err ~5e-15).
__global__ __launch_bounds__(256) void scan_kernel(const float* __restrict__ obs,
                                                   const float* __restrict__ Beta,
                                                   unsigned char* __restrict__ Gt8) {
  __shared__ float tile[64][161];   // odd stride -> conflict-free column reads
  const int tw = blockIdx.x;
  const int jg = blockIdx.y;
  const int j0 = jg * 64;
  const int t0 = tw * 128;
  const int tid = threadIdx.x;

  for (int u = tid; u < 64 * 40; u += 256) {
    int row = u / 40;
    int c4 = u % 40;
    int tloc = c4 * 4;
    int tg = t0 - 32 + tloc;
    float4 v;
    if (tg >= 0) {
      v = *(const float4*)(obs + (size_t)(j0 + row) * N_DIM + tg);
    } else {
      v = make_float4(0.f, 0.f, 0.f, 0.f);
    }
    tile[row][tloc]     = v.x;
    tile[row][tloc + 1] = v.y;
    tile[row][tloc + 2] = v.z;
    tile[row][tloc + 3] = v.w;
  }
  __syncthreads();

  const int w = tid >> 6;
  const int lane = tid & 63;
  const int j = j0 + lane;
  const float beta = Beta[j];
  const float decay = __expf(-beta);
  const int lt0 = w * 32;
  float S = 0.f;
  #pragma unroll
  for (int i = 0; i < 32; ++i) S = decay * (S + tile[lane][lt0 + i]);
  const int tg = t0 + w * 32;
  #pragma unroll
  for (int i = 0; i < 32; ++i) {
    int p = __builtin_amdgcn_cvt_pk_fp8_f32(G_SCALE * beta * S, 0.f, 0, false);
    Gt8[(size_t)(tg + i) * K_DIM + j] = (unsigned char)(p & 0xff);  // 64B wave segment
    S = decay * (S + tile[lane][lt0 + 32 + i]);
  }
}

// ---------------- NT fp8 MFMA GEMM + fused epilogue ----------------
// C[k][t] = (1/16384) * sum_j A8[k][j] * Gt8[t][j]; lam1 = softplus(C) (0 at t=0);
// writes lam1 (+ lams0 when fused), accumulates loglik.
// BM=BN=128, BK=64, 256 threads, 2x2 waves, 4x4 frags of 16x16x32 fp8.
__global__ __launch_bounds__(256) void gemm_kernel(const unsigned char* __restrict__ A8,   // [1024][1024]
                                                   const unsigned char* __restrict__ B8,   // [16384][1024]
                                                   const float* __restrict__ obs,
                                                   const float* __restrict__ mu_acc,
                                                   float* __restrict__ lam1_out,
                                                   float* __restrict__ lams0_out,          // may be null
                                                   double* __restrict__ acc_out) {
  const int tb = blockIdx.x;   // t tile (0..127)
  const int kb = blockIdx.y;   // k tile (0..7)
  const int tid = threadIdx.x;
  const int lane = tid & 63, w = tid >> 6;
  const int wm = w >> 1, wn = w & 1;
  const int ml = lane & 15, q = lane >> 4;

  __shared__ unsigned char As[128 * 64];   // 8 KB
  __shared__ unsigned char Bs[128 * 64];   // 8 KB
  __shared__ float wsum[4];

  floatx4 acc[4][4] = {};

  const unsigned char* Ab = A8 + (size_t)kb * 128 * K_DIM;
  const unsigned char* Bb = B8 + (size_t)tb * 128 * K_DIM;

  for (int kt = 0; kt < 16; ++kt) {
    const unsigned char* Ak = Ab + kt * 64;
    const unsigned char* Bk = Bb + kt * 64;
    // 512 16B-chunks per matrix; 2 per thread per matrix. LDS dst linear in lane.
    #pragma unroll
    for (int it = 0; it < 2; ++it) {
      int L = it * 256 + tid;
      int r = L >> 2;                  // tile row (64B = 4 chunks per row)
      int c = L & 3;
      int cg = c ^ ((r >> 1) & 3);     // XOR swizzle on the GLOBAL side (bank period = 2 rows)
      async_copy16(Ak + (size_t)r * K_DIM + cg * 16, &As[L * 16]);
      async_copy16(Bk + (size_t)r * K_DIM + cg * 16, &Bs[L * 16]);
    }
    __syncthreads();

    #pragma unroll
    for (int kk = 0; kk < 2; ++kk) {
      long a[4], b[4];
      const int c0 = kk * 2 + (q >> 1);
      const int sub = (q & 1) * 8;
      #pragma unroll
      for (int mf = 0; mf < 4; ++mf) {
        int r = wm * 64 + mf * 16 + ml;
        int cg = c0 ^ ((r >> 1) & 3);
        a[mf] = *(const long*)&As[r * 64 + cg * 16 + sub];   // ds_read_b64, 2-way max
      }
      #pragma unroll
      for (int nf = 0; nf < 4; ++nf) {
        int r = wn * 64 + nf * 16 + ml;
        int cg = c0 ^ ((r >> 1) & 3);
        b[nf] = *(const long*)&Bs[r * 64 + cg * 16 + sub];
      }
      #pragma unroll
      for (int mf = 0; mf < 4; ++mf)
        #pragma unroll
        for (int nf = 0; nf < 4; ++nf)
          acc[mf][nf] = __builtin_amdgcn_mfma_f32_16x16x32_fp8_fp8(a[mf], b[nf], acc[mf][nf], 0, 0, 0);
    }
    __syncthreads();
  }

  // epilogue: C/D layout col=lane&15 (t), row=q*4+reg (k)
  float lsum = 0.f;
  const int kblk = kb * 128 + wm * 64;
  const int tblk = tb * 128 + wn * 64;
  #pragma unroll
  for (int mf = 0; mf < 4; ++mf) {
    int k4 = kblk + mf * 16 + q * 4;
    floatx4 mu4 = *(const floatx4*)&mu_acc[k4];
    #pragma unroll
    for (int r = 0; r < 4; ++r) {
      int k = k4 + r;
      float mu = mu4[r] * (1.0f / 163840.0f) + 1e-5f;
      #pragma unroll
      for (int nf = 0; nf < 4; ++nf) {
        int t = tblk + nf * 16 + ml;
        float raw = acc[mf][nf][r] * INV_SCALE;
        float e = __expf(-fabsf(raw));
        float lam = fmaxf(raw, 0.f) + __logf(1.f + e);   // stable softplus, fast-math
        if (t == 0) lam = 0.f;                           // t=0 branch returns zeros
        lam1_out[(size_t)k * N_DIM + t] = lam;
        if (lams0_out) lams0_out[(size_t)k * N_DIM + t] = mu;   // fused lams0 broadcast
        float o = obs[(size_t)k * N_DIM + t];
        lsum += o * __logf(mu + lam + 1e-5f) - mu - lam;
      }
    }
  }
  #pragma unroll
  for (int off = 32; off > 0; off >>= 1) lsum += __shfl_down(lsum, off);
  if (lane == 0) wsum[w] = lsum;
  __syncthreads();
  if (tid == 0) atomicAdd(acc_out, (double)(wsum[0] + wsum[1] + wsum[2] + wsum[3]));
}

// ---------------- tail: just the loglik scalar (ws-big path) ----------------
__global__ void tail_kernel(const double* __restrict__ acc, float* __restrict__ out) {
  out[0] = (float)(*acc);
}

// ---------------- fallback finalize: lams0 broadcast + loglik (ws-small path) ----------------
__global__ __launch_bounds__(256) void finalize_kernel(const float* __restrict__ mu_acc,
                                                       const double* __restrict__ acc,
                                                       float* __restrict__ out) {
  int k = blockIdx.x;
  float mu = mu_acc[k] * (1.0f / 163840.0f) + 1e-5f;
  float* dst = out + 1 + (size_t)k * N_DIM;
  int tid = threadIdx.x;
  if (tid < 3) dst[tid] = mu;
  float4 v4 = make_float4(mu, mu, mu, mu);
  for (int t = 3 + tid * 4; t + 3 < N_DIM; t += 256 * 4) *(float4*)(dst + t) = v4;
  if (tid == 3) dst[N_DIM - 1] = mu;
  if (blockIdx.x == 0 && tid == 4) out[0] = (float)(*acc);
}

extern "C" void kernel_launch(void* const* d_in, const int* in_sizes, int n_in,
                              void* d_out, int out_size, void* d_ws, size_t ws_size,
                              hipStream_t stream) {
  const float* obs   = (const float*)d_in[0];   // [1024][16384]
  const float* Beta  = (const float*)d_in[1];   // [1024]
  const float* Alpha = (const float*)d_in[2];   // [1024][1024]
  float* out = (float*)d_out;                   // [0]=loglik, lams0 (K*N), lam1 (K*N)

  double* acc   = (double*)d_ws;                // 8 B
  float* mu_acc = (float*)((char*)d_ws + 16);   // 4 KB

  // Gt8 (16 MB) + A8 (1 MB) placement: d_ws when it fits (enables fused lams0),
  // else inside the lams0 output region (overwritten by finalize afterwards).
  const bool ws_big = ws_size >= (size_t)(8192 + 17 * 1024 * 1024 + 4096);
  unsigned char* Gt8;
  unsigned char* A8;
  if (ws_big) {
    Gt8 = (unsigned char*)d_ws + 8192;
    A8  = Gt8 + (size_t)N_DIM * K_DIM;
  } else {
    Gt8 = (unsigned char*)(out + 4);
    A8  = Gt8 + (size_t)N_DIM * K_DIM;
  }

  hipMemsetAsync(d_ws, 0, 16, stream);   // zero the loglik accumulator

  mu_convert<<<dim3(K_DIM), 256, 0, stream>>>(obs, Alpha, mu_acc, (int*)A8);

  scan_kernel<<<dim3(N_DIM / 128, K_DIM / 64), 256, 0, stream>>>(obs, Beta, Gt8);

  gemm_kernel<<<dim3(N_DIM / 128, K_DIM / 128), 256, 0, stream>>>(
      A8, Gt8, obs, mu_acc,
      out + 1 + (size_t)K_DIM * N_DIM,
      ws_big ? (out + 1) : nullptr,
      acc);

  if (ws_big) {
    tail_kernel<<<1, 1, 0, stream>>>(acc, out);
  } else {
    finalize_kernel<<<dim3(K_DIM), 256, 0, stream>>>(mu_acc, acc, out);
  }
}